// Round 9
// baseline (35.684 us; speedup 1.0000x reference)
//
#include <hip/hip_runtime.h>

#define B 8
#define K 8
#define H 384
#define W 384
#define HW (H*W)                 // 147456 pixels per batch
#define NCPP 16                  // chunks per (b,k) plane in stage A
#define GROUPS_PER_B (HW/4)      // 36864 float4-groups per batch

typedef float f32x4 __attribute__((ext_vector_type(4)));

// ws layout (floats): [0, B*K*NCPP*4) stage-A partials,
//   ws[((b*K+k)*NCPP + ch)*4 + comp], comp = {sum_m, sum_mdx, sum_mdy, sum_md}

__device__ __forceinline__ void euler2mat(float ax, float ay, float az, float R[9]) {
    float cx = cosf(ax), sx = sinf(ax);
    float cy = cosf(ay), sy = sinf(ay);
    float cz = cosf(az), sz = sinf(az);
    // R = xmat @ ymat @ zmat
    R[0] = cy*cz;              R[1] = -cy*sz;             R[2] = sy;
    R[3] = cx*sz + sx*sy*cz;   R[4] = cx*cz - sx*sy*sz;   R[5] = -sx*cy;
    R[6] = sx*sz - cx*sy*cz;   R[7] = sx*cz + cx*sy*sz;   R[8] = cx*cy;
}

// ---------------- Stage A: byte-identical to round 7 (measured: ~7 us, at roofline) ----------------
__global__ __launch_bounds__(256) void k_reduce(const float* __restrict__ mask,
                                                const float* __restrict__ depth,
                                                float* __restrict__ ws) {
    const int chunk = blockIdx.x, k = blockIdx.y, b = blockIdx.z;
    const int tid = threadIdx.x;

    const float4* m4 = (const float4*)(mask + ((size_t)(b*K + k)) * HW);
    const float4* d4 = (const float4*)(depth + (size_t)b * HW);

    float s0 = 0.f, s1 = 0.f, s2 = 0.f, s3 = 0.f;
    const float inv = 2.f / W;

#pragma unroll
    for (int r = 0; r < 9; ++r) {
        int g = (chunk * 9 + r) * 256 + tid;   // float4-group in [0, 36864)
        float4 mv = m4[g];
        float4 dv = d4[g];
        int i0 = g * 4;
        int h = i0 / W;
        int w0 = i0 - h * W;                   // 4 | W: all 4 pixels share row h
        float py = 2.f * (h + 0.5f) * (1.f / H) - 1.f;
        float px0 = 2.f * (w0 + 0.5f) * (1.f / W) - 1.f;
        float mm[4] = {mv.x, mv.y, mv.z, mv.w};
        float dd[4] = {dv.x, dv.y, dv.z, dv.w};
#pragma unroll
        for (int j = 0; j < 4; ++j) {
            float m = mm[j];
            float t = m * dd[j];
            float px = px0 + j * inv;
            s0 += m; s1 += t * px; s2 += t * py; s3 += t;
        }
    }

    for (int off = 32; off > 0; off >>= 1) {
        s0 += __shfl_down(s0, off);
        s1 += __shfl_down(s1, off);
        s2 += __shfl_down(s2, off);
        s3 += __shfl_down(s3, off);
    }
    __shared__ float sd[16];
    int lane = tid & 63, wid = tid >> 6;
    if (lane == 0) { sd[wid*4+0]=s0; sd[wid*4+1]=s1; sd[wid*4+2]=s2; sd[wid*4+3]=s3; }
    __syncthreads();
    if (tid < 4) {
        float v = sd[tid] + sd[4 + tid] + sd[8 + tid] + sd[12 + tid];
        ws[(((b*K + k) * NCPP) + chunk) * 4 + tid] = v;
    }
}

// ---------------- DIAGNOSTIC: k_flow with body repeated 3x (idempotent) ----------------
// Purpose: lift dur above the harness fill dispatches (~40 us) so rocprof's top-5
// shows FETCH/WRITE/VALUBusy/Occupancy for the flow work. Values stored are
// identical each rep; asm memory clobbers prevent CSE across reps.
__global__ __launch_bounds__(256) void k_flow(const float* __restrict__ mask,
                                              const float* __restrict__ depth,
                                              const float* __restrict__ T,
                                              const float* __restrict__ Tc,
                                              const float* __restrict__ ws,
                                              float* __restrict__ out) {
    const int b = blockIdx.y;
    const int tid = threadIdx.x;

    __shared__ float sP[512];                 // this b's partials [k][ch][comp]
    __shared__ float s32[32];
    __shared__ float sp[108];                 // 8 x 12 per-k params + 12 camera

    // ---- fold first (tiny), pixel loads live inside the rep loop ----
    if (tid < 128)
        ((float4*)sP)[tid] = ((const float4*)(ws + (size_t)b * 512))[tid];
    __syncthreads();

    if (tid < 32) {
        int k = tid >> 2, comp = tid & 3;
        float s = 0.f;
#pragma unroll
        for (int ch = 0; ch < NCPP; ++ch) s += sP[(k * NCPP + ch) * 4 + comp];
        s32[tid] = s;
    }
    __syncthreads();

    if (tid < 8) {
        int k = tid;
        float mass = s32[k*4 + 0] + 1e-6f;
        float p0 = s32[k*4 + 1] / mass;
        float p1 = s32[k*4 + 2] / mass;
        float p2 = s32[k*4 + 3] / mass;
        const float* Tk = T + (b*K + k) * 6;
        float R[9];
        euler2mat(Tk[3], Tk[4], Tk[5], R);
        float Rp0 = R[0]*p0 + R[1]*p1 + R[2]*p2;
        float Rp1 = R[3]*p0 + R[4]*p1 + R[5]*p2;
        float Rp2 = R[6]*p0 + R[7]*p1 + R[8]*p2;
        float* o = sp + k * 12;
        o[0] = R[0] - 1.f; o[1] = R[1];       o[2] = R[2];
        o[3] = R[3];       o[4] = R[4] - 1.f; o[5] = R[5];
        o[6] = R[6];       o[7] = R[7];       o[8] = R[8] - 1.f;
        o[9]  = p0 + Tk[0] - Rp0;
        o[10] = p1 + Tk[1] - Rp1;
        o[11] = p2 + Tk[2] - Rp2;
    } else if (tid == 8) {
        const float* Tb = Tc + b * 9;
        float R[9];
        euler2mat(Tb[3], Tb[4], Tb[5], R);
        float pc0 = Tb[6], pc1 = Tb[7], pc2 = Tb[8];
        float* o = sp + 96;
#pragma unroll
        for (int i = 0; i < 9; ++i) o[i] = R[i];
        o[9]  = pc0 + Tb[0] - (R[0]*pc0 + R[1]*pc1 + R[2]*pc2);
        o[10] = pc1 + Tb[1] - (R[3]*pc0 + R[4]*pc1 + R[5]*pc2);
        o[11] = pc2 + Tb[2] - (R[6]*pc0 + R[7]*pc1 + R[8]*pc2);
    }
    __syncthreads();

    const int g = blockIdx.x * 256 + tid;     // [0, 36864)
    const int i0 = g * 4;
    const int h = i0 / W;
    const int w0 = i0 - h * W;
    const float py = 2.f * (h + 0.5f) * (1.f / H) - 1.f;
    const float inv = 2.f / W;
    const float px0 = 2.f * (w0 + 0.5f) * (1.f / W) - 1.f;

#pragma unroll 1
    for (int rep = 0; rep < 3; ++rep) {
        asm volatile("" ::: "memory");        // defeat CSE: force real reloads/recompute

        float4 dv = ((const float4*)(depth + (size_t)b * HW))[g];
        float4 mf[K];
#pragma unroll
        for (int k = 0; k < K; ++k)
            mf[k] = ((const float4*)(mask + ((size_t)(b*K + k)) * HW))[g];

        float dd[4] = {dv.x, dv.y, dv.z, dv.w};
        float res[8];
#pragma unroll
        for (int j = 0; j < 4; ++j) {
            float px = px0 + j * inv;
            float d = dd[j];
            float wx = d * px, wy = d * py, wz = d;
            float ax = wx, ay = wy, az = wz;
#pragma unroll
            for (int k = 0; k < K; ++k) {
                const float* P = sp + k * 12;
                float m = (j == 0) ? mf[k].x : (j == 1) ? mf[k].y : (j == 2) ? mf[k].z : mf[k].w;
                float rx = P[0]*wx + P[1]*wy + P[2]*wz + P[9];
                float ry = P[3]*wx + P[4]*wy + P[5]*wz + P[10];
                float rz = P[6]*wx + P[7]*wy + P[8]*wz + P[11];
                ax += m * rx; ay += m * ry; az += m * rz;
            }
            const float* C = sp + 96;
            float ox = C[0]*ax + C[1]*ay + C[2]*az + C[9];
            float oy = C[3]*ax + C[4]*ay + C[5]*az + C[10];
            float oz = C[6]*ax + C[7]*ay + C[8]*az + C[11];
            res[j*2 + 0] = ox / oz - px;
            res[j*2 + 1] = oy / oz - py;
        }

        f32x4* o4 = (f32x4*)(out + ((size_t)b * HW + i0) * 2);
        f32x4 v0 = {res[0], res[1], res[2], res[3]};
        f32x4 v1 = {res[4], res[5], res[6], res[7]};
        __builtin_nontemporal_store(v0, o4);
        __builtin_nontemporal_store(v1, o4 + 1);
    }
}

extern "C" void kernel_launch(void* const* d_in, const int* in_sizes, int n_in,
                              void* d_out, int out_size, void* d_ws, size_t ws_size,
                              hipStream_t stream) {
    // inputs: im (unused), mask, depth, T, Tc — all float32
    const float* mask  = (const float*)d_in[1];
    const float* depth = (const float*)d_in[2];
    const float* T     = (const float*)d_in[3];
    const float* Tc    = (const float*)d_in[4];
    float* ws  = (float*)d_ws;
    float* out = (float*)d_out;

    k_reduce<<<dim3(NCPP, K, B), 256, 0, stream>>>(mask, depth, ws);
    k_flow<<<dim3(GROUPS_PER_B / 256, B), 256, 0, stream>>>(mask, depth, T, Tc, ws, out);
}

// Round 10
// 25.928 us; speedup vs baseline: 1.3763x; 1.3763x over previous
//
#include <hip/hip_runtime.h>

#define B 8
#define K 8
#define H 384
#define W 384
#define HW (H*W)                 // 147456 pixels per batch
#define NCPP 16                  // chunks per (b,k) plane in stage A
#define GROUPS_PER_B (HW/4)      // 36864 float4-groups per batch

typedef float f32x4 __attribute__((ext_vector_type(4)));

// Non-temporal float4 load: bypasses L2/L3 allocation. Critical here because the
// harness's 268 MB flush-fill leaves L3 fully DIRTY before every replay; regular
// streaming reads then pay a writeback per allocated line (~2x traffic). Mask
// bytes are read exactly once per kernel -> never worth caching.
__device__ __forceinline__ float4 ntload4(const float* p) {
    f32x4 v = __builtin_nontemporal_load((const f32x4*)p);
    return make_float4(v.x, v.y, v.z, v.w);
}

// ws layout (floats): [0, B*K*NCPP*4) stage-A partials,
//   ws[((b*K+k)*NCPP + ch)*4 + comp], comp = {sum_m, sum_mdx, sum_mdy, sum_md}

__device__ __forceinline__ void euler2mat(float ax, float ay, float az, float R[9]) {
    float cx = cosf(ax), sx = sinf(ax);
    float cy = cosf(ay), sy = sinf(ay);
    float cz = cosf(az), sz = sinf(az);
    // R = xmat @ ymat @ zmat
    R[0] = cy*cz;              R[1] = -cy*sz;             R[2] = sy;
    R[3] = cx*sz + sx*sy*cz;   R[4] = cx*cz - sx*sy*sz;   R[5] = -sx*cy;
    R[6] = sx*sz - cx*sy*cz;   R[7] = sx*cz + cx*sy*sz;   R[8] = cx*cy;
}

// ---------------- Stage A: round-7 arithmetic, mask loads now non-temporal ----------------
__global__ __launch_bounds__(256) void k_reduce(const float* __restrict__ mask,
                                                const float* __restrict__ depth,
                                                float* __restrict__ ws) {
    const int chunk = blockIdx.x, k = blockIdx.y, b = blockIdx.z;
    const int tid = threadIdx.x;

    const float* mbase = mask + ((size_t)(b*K + k)) * HW;
    const float4* d4 = (const float4*)(depth + (size_t)b * HW);

    float s0 = 0.f, s1 = 0.f, s2 = 0.f, s3 = 0.f;
    const float inv = 2.f / W;

#pragma unroll
    for (int r = 0; r < 9; ++r) {
        int g = (chunk * 9 + r) * 256 + tid;   // float4-group in [0, 36864)
        float4 mv = ntload4(mbase + (size_t)g * 4);
        float4 dv = d4[g];
        int i0 = g * 4;
        int h = i0 / W;
        int w0 = i0 - h * W;                   // 4 | W: all 4 pixels share row h
        float py = 2.f * (h + 0.5f) * (1.f / H) - 1.f;
        float px0 = 2.f * (w0 + 0.5f) * (1.f / W) - 1.f;
        float mm[4] = {mv.x, mv.y, mv.z, mv.w};
        float dd[4] = {dv.x, dv.y, dv.z, dv.w};
#pragma unroll
        for (int j = 0; j < 4; ++j) {
            float m = mm[j];
            float t = m * dd[j];
            float px = px0 + j * inv;
            s0 += m; s1 += t * px; s2 += t * py; s3 += t;
        }
    }

    for (int off = 32; off > 0; off >>= 1) {
        s0 += __shfl_down(s0, off);
        s1 += __shfl_down(s1, off);
        s2 += __shfl_down(s2, off);
        s3 += __shfl_down(s3, off);
    }
    __shared__ float sd[16];
    int lane = tid & 63, wid = tid >> 6;
    if (lane == 0) { sd[wid*4+0]=s0; sd[wid*4+1]=s1; sd[wid*4+2]=s2; sd[wid*4+3]=s3; }
    __syncthreads();
    if (tid < 4) {
        float v = sd[tid] + sd[4 + tid] + sd[8 + tid] + sd[12 + tid];
        ws[(((b*K + k) * NCPP) + chunk) * 4 + tid] = v;
    }
}

// ---------------- Stage B+C: round-7 arithmetic, mask loads now non-temporal ----------------
__global__ __launch_bounds__(256) void k_flow(const float* __restrict__ mask,
                                              const float* __restrict__ depth,
                                              const float* __restrict__ T,
                                              const float* __restrict__ Tc,
                                              const float* __restrict__ ws,
                                              float* __restrict__ out) {
    const int b = blockIdx.y;
    const int tid = threadIdx.x;

    __shared__ float sP[512];                 // this b's partials [k][ch][comp]
    __shared__ float s32[32];
    __shared__ float sp[108];                 // 8 x 12 per-k params + 12 camera

    // ---- issue pixel loads FIRST so the fold hides under them ----
    int g = blockIdx.x * 256 + tid;           // [0, 36864)
    int i0 = g * 4;
    float4 dv = ((const float4*)(depth + (size_t)b * HW))[g];
    float4 mf[K];
#pragma unroll
    for (int k = 0; k < K; ++k)
        mf[k] = ntload4(mask + ((size_t)(b*K + k)) * HW + (size_t)g * 4);

    // ---- stage partials to LDS (coalesced, 128 x float4) ----
    if (tid < 128)
        ((float4*)sP)[tid] = ((const float4*)(ws + (size_t)b * 512))[tid];
    __syncthreads();

    // ---- fold: same per-accumulator add order as round-2 k_params (ch ascending) ----
    if (tid < 32) {
        int k = tid >> 2, comp = tid & 3;
        float s = 0.f;
#pragma unroll
        for (int ch = 0; ch < NCPP; ++ch) s += sP[(k * NCPP + ch) * 4 + comp];
        s32[tid] = s;
    }
    __syncthreads();

    if (tid < 8) {
        int k = tid;
        float mass = s32[k*4 + 0] + 1e-6f;
        float p0 = s32[k*4 + 1] / mass;
        float p1 = s32[k*4 + 2] / mass;
        float p2 = s32[k*4 + 3] / mass;
        const float* Tk = T + (b*K + k) * 6;
        float R[9];
        euler2mat(Tk[3], Tk[4], Tk[5], R);
        float Rp0 = R[0]*p0 + R[1]*p1 + R[2]*p2;
        float Rp1 = R[3]*p0 + R[4]*p1 + R[5]*p2;
        float Rp2 = R[6]*p0 + R[7]*p1 + R[8]*p2;
        float* o = sp + k * 12;
        o[0] = R[0] - 1.f; o[1] = R[1];       o[2] = R[2];
        o[3] = R[3];       o[4] = R[4] - 1.f; o[5] = R[5];
        o[6] = R[6];       o[7] = R[7];       o[8] = R[8] - 1.f;
        o[9]  = p0 + Tk[0] - Rp0;
        o[10] = p1 + Tk[1] - Rp1;
        o[11] = p2 + Tk[2] - Rp2;
    } else if (tid == 8) {
        const float* Tb = Tc + b * 9;
        float R[9];
        euler2mat(Tb[3], Tb[4], Tb[5], R);
        float pc0 = Tb[6], pc1 = Tb[7], pc2 = Tb[8];
        float* o = sp + 96;
#pragma unroll
        for (int i = 0; i < 9; ++i) o[i] = R[i];
        o[9]  = pc0 + Tb[0] - (R[0]*pc0 + R[1]*pc1 + R[2]*pc2);
        o[10] = pc1 + Tb[1] - (R[3]*pc0 + R[4]*pc1 + R[5]*pc2);
        o[11] = pc2 + Tb[2] - (R[6]*pc0 + R[7]*pc1 + R[8]*pc2);
    }
    __syncthreads();

    // ---- per-pixel transform (identical arithmetic to round 2) ----
    int h = i0 / W;
    int w0 = i0 - h * W;
    float py = 2.f * (h + 0.5f) * (1.f / H) - 1.f;
    const float inv = 2.f / W;
    float px0 = 2.f * (w0 + 0.5f) * (1.f / W) - 1.f;

    float dd[4] = {dv.x, dv.y, dv.z, dv.w};
    float res[8];
#pragma unroll
    for (int j = 0; j < 4; ++j) {
        float px = px0 + j * inv;
        float d = dd[j];
        float wx = d * px, wy = d * py, wz = d;
        float ax = wx, ay = wy, az = wz;
#pragma unroll
        for (int k = 0; k < K; ++k) {
            const float* P = sp + k * 12;
            float m = (j == 0) ? mf[k].x : (j == 1) ? mf[k].y : (j == 2) ? mf[k].z : mf[k].w;
            float rx = P[0]*wx + P[1]*wy + P[2]*wz + P[9];
            float ry = P[3]*wx + P[4]*wy + P[5]*wz + P[10];
            float rz = P[6]*wx + P[7]*wy + P[8]*wz + P[11];
            ax += m * rx; ay += m * ry; az += m * rz;
        }
        const float* C = sp + 96;
        float ox = C[0]*ax + C[1]*ay + C[2]*az + C[9];
        float oy = C[3]*ax + C[4]*ay + C[5]*az + C[10];
        float oz = C[6]*ax + C[7]*ay + C[8]*az + C[11];
        res[j*2 + 0] = ox / oz - px;
        res[j*2 + 1] = oy / oz - py;
    }

    // non-temporal stores: out is write-once
    f32x4* o4 = (f32x4*)(out + ((size_t)b * HW + i0) * 2);
    f32x4 v0 = {res[0], res[1], res[2], res[3]};
    f32x4 v1 = {res[4], res[5], res[6], res[7]};
    __builtin_nontemporal_store(v0, o4);
    __builtin_nontemporal_store(v1, o4 + 1);
}

extern "C" void kernel_launch(void* const* d_in, const int* in_sizes, int n_in,
                              void* d_out, int out_size, void* d_ws, size_t ws_size,
                              hipStream_t stream) {
    // inputs: im (unused), mask, depth, T, Tc — all float32
    const float* mask  = (const float*)d_in[1];
    const float* depth = (const float*)d_in[2];
    const float* T     = (const float*)d_in[3];
    const float* Tc    = (const float*)d_in[4];
    float* ws  = (float*)d_ws;
    float* out = (float*)d_out;

    k_reduce<<<dim3(NCPP, K, B), 256, 0, stream>>>(mask, depth, ws);
    k_flow<<<dim3(GROUPS_PER_B / 256, B), 256, 0, stream>>>(mask, depth, T, Tc, ws, out);
}